// Round 3
// baseline (115.801 us; speedup 1.0000x reference)
//
#include <hip/hip_runtime.h>

// SpatialShiftConvBlock (B=8,T=64,N=21,C=128,F=256), ALL float32:
//   xs[b,t,n,c] = x[b,t,(n - c%21) mod 21, c]       (per-channel circular roll)
//   y  = xs @ W + b                                 (1x1 conv == GEMM K=128)
//   y  = (y - mean)*rsqrt(var + 1e-3)*gamma + beta  (BN training stats over B,T,N)
//   out = relu(y)
//
// R31: fix R30's row-split bug (rhalf=1,g=3 r0 was 18, double-computing row 18
// and never writing row 20 -> absmax 4.65). Intended split:
//   rhalf0 rows 0..10 : r0={0,3,6,9},     nv={3,3,3,2}
//   rhalf1 rows 11..20: r0={11,14,17,19}, nv={3,3,2,2}
// Design (from R30): grid=1024, blockIdx=(bt,row-half) -> 4 blocks/CU,
// 16 waves/CU (2x TLP vs R29). Per-thread chain 1536 FMA, 12 accumulators.
// Each wave covers all 64 channel quads (W row reads stay coalesced/minimal).
// Harness's 256MiB ws re-poison (fillBufferAligned ~41us) is a fixed tax.

#define NPOS 21
#define CIN  128
#define FOUT 256
#define BT   512            // B*T
#define M_TOTAL 10752       // BT*NPOS
#define BN_EPS 1e-3f
#define LROW 42             // duplicated LDS row length (2*NPOS)

__global__ __launch_bounds__(256) void k_conv(const float* __restrict__ x,
                                              const float* __restrict__ W,
                                              const float* __restrict__ bias,
                                              float* __restrict__ y,
                                              float* __restrict__ ws)
{
    __shared__ float xsT[CIN * LROW];      // 21 KB, transposed + duplicated
    __shared__ float sumL[4 * FOUT];       // 4 KB per-wave partial sums
    __shared__ float sqL [4 * FOUT];       // 4 KB

    const int bt    = blockIdx.x >> 1;
    const int rhalf = blockIdx.x & 1;      // adjacent blocks share the slab in L2
    const int t     = threadIdx.x;

    const float* xin = x + (size_t)bt * (NPOS * CIN);
    for (int i = t; i < NPOS * CIN; i += 256) {
        float v = xin[i];                  // fully coalesced
        int n = i >> 7;                    // i = n*128 + c
        int c = i & (CIN - 1);
        xsT[c * LROW + n]        = v;
        xsT[c * LROW + n + NPOS] = v;      // duplicate: rotation never wraps
    }
    __syncthreads();

    const int g  = t >> 6;                 // wave id = row group
    const int fb = (t & 63) << 2;          // channel quad base (64 quads = full F)
    int r0, nv;
    if (rhalf == 0) { r0 = g * 3;                           nv = (g == 3) ? 2 : 3; }
    else            { r0 = 11 + g * 3 - ((g == 3) ? 1 : 0); nv = (g >= 2) ? 2 : 3; }

    float acc[3][4];
    #pragma unroll
    for (int j = 0; j < 3; j++)
        acc[j][0] = acc[j][1] = acc[j][2] = acc[j][3] = 0.0f;

    const float* Wp   = W + fb;            // wave reads a full 1KB W row per c
    const float* xrow = xsT;
    int start = r0;                        // (r0 - c) mod 21, kept incrementally
    #pragma unroll 4
    for (int c = 0; c < CIN; c++) {
        const float4 wv = *(const float4*)Wp;
        // wave-uniform broadcast reads, consecutive floats (ds_read2 fusion);
        // j=2 may be a garbage row (masked at store), read always in-bounds
        float xv0 = xrow[start];
        float xv1 = xrow[start + 1];
        float xv2 = xrow[start + 2];
        acc[0][0] = fmaf(xv0, wv.x, acc[0][0]);
        acc[0][1] = fmaf(xv0, wv.y, acc[0][1]);
        acc[0][2] = fmaf(xv0, wv.z, acc[0][2]);
        acc[0][3] = fmaf(xv0, wv.w, acc[0][3]);
        acc[1][0] = fmaf(xv1, wv.x, acc[1][0]);
        acc[1][1] = fmaf(xv1, wv.y, acc[1][1]);
        acc[1][2] = fmaf(xv1, wv.z, acc[1][2]);
        acc[1][3] = fmaf(xv1, wv.w, acc[1][3]);
        acc[2][0] = fmaf(xv2, wv.x, acc[2][0]);
        acc[2][1] = fmaf(xv2, wv.y, acc[2][1]);
        acc[2][2] = fmaf(xv2, wv.z, acc[2][2]);
        acc[2][3] = fmaf(xv2, wv.w, acc[2][3]);
        Wp   += FOUT;
        xrow += LROW;
        start = (start == 0) ? (NPOS - 1) : (start - 1);
    }

    const float4 bv = *(const float4*)(bias + fb);
    float ls0 = 0.f, ls1 = 0.f, ls2 = 0.f, ls3 = 0.f;
    float lq0 = 0.f, lq1 = 0.f, lq2 = 0.f, lq3 = 0.f;
    float* yout = y + (size_t)bt * (NPOS * FOUT);
    #pragma unroll
    for (int j = 0; j < 3; j++) {
        if (j < nv) {                      // wave-uniform branch
            float4 o;
            o.x = acc[j][0] + bv.x;
            o.y = acc[j][1] + bv.y;
            o.z = acc[j][2] + bv.z;
            o.w = acc[j][3] + bv.w;
            *(float4*)(yout + (size_t)(r0 + j) * FOUT + fb) = o;   // coalesced
            ls0 += o.x; lq0 += o.x * o.x;
            ls1 += o.y; lq1 += o.y * o.y;
            ls2 += o.z; lq2 += o.z * o.z;
            ls3 += o.w; lq3 += o.w * o.w;
        }
    }
    *(float4*)(sumL + g * FOUT + fb) = make_float4(ls0, ls1, ls2, ls3);
    *(float4*)(sqL  + g * FOUT + fb) = make_float4(lq0, lq1, lq2, lq3);
    __syncthreads();

    // cross-wave reduce, one atomic per channel per block
    float s = sumL[t] + sumL[FOUT + t] + sumL[2 * FOUT + t] + sumL[3 * FOUT + t];
    float q = sqL[t]  + sqL[FOUT + t]  + sqL[2 * FOUT + t]  + sqL[3 * FOUT + t];
    atomicAdd(ws + t, s);
    atomicAdd(ws + FOUT + t, q);
}

__global__ void k_zero(float* __restrict__ ws)
{
    ws[blockIdx.x * 256 + threadIdx.x] = 0.0f;
}

#define BN_BLOCKS 1344      // 1344 * 512 float4 = 688128 = 10752*256/4 exactly

__global__ __launch_bounds__(256) void k_bnapply(float* __restrict__ y,
                                                 const float* __restrict__ ws,
                                                 const float* __restrict__ gamma,
                                                 const float* __restrict__ beta)
{
    const int t  = threadIdx.x;
    const int fb = (t & 63) << 2;          // this thread's fixed channel quad
    const float4 sm = *(const float4*)(ws + fb);
    const float4 sq = *(const float4*)(ws + FOUT + fb);
    const float4 gm = *(const float4*)(gamma + fb);
    const float4 be = *(const float4*)(beta + fb);
    const float invM = 1.0f / (float)M_TOTAL;

    float sc[4], bs[4];
    {
        float m0 = sm.x * invM, m1 = sm.y * invM, m2 = sm.z * invM, m3 = sm.w * invM;
        float v0 = fmaf(-m0, m0, sq.x * invM);
        float v1 = fmaf(-m1, m1, sq.y * invM);
        float v2 = fmaf(-m2, m2, sq.z * invM);
        float v3 = fmaf(-m3, m3, sq.w * invM);
        sc[0] = rsqrtf(v0 + BN_EPS) * gm.x;  bs[0] = be.x - m0 * sc[0];
        sc[1] = rsqrtf(v1 + BN_EPS) * gm.y;  bs[1] = be.y - m1 * sc[1];
        sc[2] = rsqrtf(v2 + BN_EPS) * gm.z;  bs[2] = be.z - m2 * sc[2];
        sc[3] = rsqrtf(v3 + BN_EPS) * gm.w;  bs[3] = be.w - m3 * sc[3];
    }

    float4* y4 = (float4*)y;
    #pragma unroll
    for (int it = 0; it < 2; it++) {
        int g = blockIdx.x * 512 + it * 256 + t;   // g%64 == t&63 -> quad matches fb
        float4 v = y4[g];
        v.x = fmaxf(fmaf(v.x, sc[0], bs[0]), 0.0f);
        v.y = fmaxf(fmaf(v.y, sc[1], bs[1]), 0.0f);
        v.z = fmaxf(fmaf(v.z, sc[2], bs[2]), 0.0f);
        v.w = fmaxf(fmaf(v.w, sc[3], bs[3]), 0.0f);
        y4[g] = v;
    }
}

// Template-named symbol kept defined (harness-compat; not launched).
extern "C" __global__ void SpatialShiftConvBlock_71923522339050_kernel() {}

extern "C" void kernel_launch(void* const* d_in, const int* in_sizes, int n_in,
                              void* d_out, int out_size, void* d_ws, size_t ws_size,
                              hipStream_t stream) {
    float* y  = (float*)d_out;             // FLOAT32 output
    float* ws = (float*)d_ws;              // 512 floats: [sum | sumsq]
    k_zero<<<2, 256, 0, stream>>>(ws);
    k_conv<<<2 * BT, 256, 0, stream>>>((const float*)d_in[0], (const float*)d_in[1],
                                       (const float*)d_in[2], y, ws);
    k_bnapply<<<BN_BLOCKS, 256, 0, stream>>>(y, ws,
                                             (const float*)d_in[3], (const float*)d_in[4]);
}